// Round 8
// baseline (218.342 us; speedup 1.0000x reference)
//
#include <hip/hip_runtime.h>
#include <hip/hip_bf16.h>

#define LRELU_ALPHA 0.2f

typedef __attribute__((ext_vector_type(8))) short short8;
typedef __attribute__((ext_vector_type(4))) short short4v;
typedef __attribute__((ext_vector_type(4))) float f32x4;

__device__ __forceinline__ float bf2f(unsigned short u) {
  union { unsigned int i; float f; } x;
  x.i = ((unsigned int)u) << 16;
  return x.f;
}
__device__ __forceinline__ short f2bf(float f) {
  __hip_bfloat16 b = __float2bfloat16(f);
  union { __hip_bfloat16 b; short s; } u;
  u.b = b;
  return u.s;
}

// ---------------- K0a: Wt[f][t] = bf16(W[t][f]) ----------------
__global__ __launch_bounds__(256) void k0_wt(const float* __restrict__ W,
                                             __hip_bfloat16* __restrict__ Wt) {
  int t = blockIdx.x, f = threadIdx.x;
  Wt[f * 256 + t] = __float2bfloat16(W[t * 256 + f]);
}

// ---------------- K0b: Wa ----------------
__global__ __launch_bounds__(64) void k0_wa(const float* __restrict__ W,
                                            const float* __restrict__ a,
                                            float* __restrict__ Wa) {
  int t = blockIdx.x, lane = threadIdx.x;
  float4 wv = *reinterpret_cast<const float4*>(W + t * 256 + lane * 4);
  float4 a1 = *reinterpret_cast<const float4*>(a + lane * 4);
  float4 a2 = *reinterpret_cast<const float4*>(a + 256 + lane * 4);
  float p1 = wv.x * a1.x + wv.y * a1.y + wv.z * a1.z + wv.w * a1.w;
  float p2 = wv.x * a2.x + wv.y * a2.y + wv.z * a2.z + wv.w * a2.w;
  #pragma unroll
  for (int off = 32; off; off >>= 1) {
    p1 += __shfl_down(p1, off);
    p2 += __shfl_down(p2, off);
  }
  if (lane == 0) { Wa[t] = p1; Wa[256 + t] = p2; }
}

// ---------------- K0c: adj_norm (7x7) ----------------
__global__ __launch_bounds__(64) void k0_adj(const float* __restrict__ B,
                                             float* __restrict__ adjn) {
  int t = threadIdx.x;
  float v = 0.f;
  if (t < 49) v = B[t] + (((t / 7) == (t % 7)) ? 1.f : 0.f);
  float mn = (t < 49) ? v : 1e30f;
  float mx = (t < 49) ? v : -1e30f;
  #pragma unroll
  for (int off = 32; off; off >>= 1) {
    mn = fminf(mn, __shfl_xor(mn, off));
    mx = fmaxf(mx, __shfl_xor(mx, off));
  }
  float scaled = (v - mn) / (mx - mn);
  __shared__ float adj[49];
  __shared__ float dis[7];
  if (t < 49) adj[t] = scaled;
  __syncthreads();
  if (t < 7) {
    float s = 0.f;
    #pragma unroll
    for (int j = 0; j < 7; ++j) s += adj[t * 7 + j];
    dis[t] = 1.0f / sqrtf(s);
  }
  __syncthreads();
  if (t < 49) adjn[t] = adj[t] * dis[t / 7] * dis[t % 7];
}

// ---------------- K1s: s1/s2 streaming pass (proven roofline) ----------------
__global__ __launch_bounds__(256) void k1s(const float* __restrict__ h,
                                           const float* __restrict__ Wa,
                                           float* __restrict__ s1g,
                                           float* __restrict__ s2g) {
  const int blk = blockIdx.x;
  const int n = blk >> 4, cs = blk & 15;
  const int tid = threadIdx.x;
  const int lane = tid & 63, wave = tid >> 6;
  float wa1[4], wa2[4];
  #pragma unroll
  for (int q = 0; q < 4; ++q) {
    wa1[q] = Wa[lane * 4 + q];
    wa2[q] = Wa[256 + lane * 4 + q];
  }
  #pragma unroll
  for (int ci = 0; ci < 4; ++ci) {
    int c = cs * 16 + wave * 4 + ci;
    const float4* src =
        reinterpret_cast<const float4*>(h + (size_t)(n * 256 + c) * 1792 + lane * 28);
    float4 x[7];
    #pragma unroll
    for (int i = 0; i < 7; ++i) x[i] = src[i];
    const float* xf = reinterpret_cast<const float*>(x);
    float p1[7], p2[7];
    #pragma unroll
    for (int v = 0; v < 7; ++v) { p1[v] = 0.f; p2[v] = 0.f; }
    #pragma unroll
    for (int dt = 0; dt < 4; ++dt)
      #pragma unroll
      for (int v = 0; v < 7; ++v) {
        float val = xf[dt * 7 + v];
        p1[v] += val * wa1[dt];
        p2[v] += val * wa2[dt];
      }
    #pragma unroll
    for (int v = 0; v < 7; ++v) {
      #pragma unroll
      for (int off = 32; off; off >>= 1) {
        p1[v] += __shfl_xor(p1[v], off);
        p2[v] += __shfl_xor(p2[v], off);
      }
    }
    if (lane == 0) {
      #pragma unroll
      for (int v = 0; v < 7; ++v) {
        s1g[(n * 7 + v) * 256 + c] = p1[v];
        s2g[(n * 7 + v) * 256 + c] = p2[v];
      }
    }
  }
}

// ---------------- K2: softmax over c ----------------
__global__ __launch_bounds__(256) void k2_soft(const float* __restrict__ s1g,
                                               const float* __restrict__ s2g,
                                               float* __restrict__ att) {
  __shared__ float s1L[1792], s2L[1792];
  const int n = blockIdx.x, tid = threadIdx.x;
  for (int idx = tid; idx < 1792; idx += 256) {
    s1L[idx] = s1g[n * 1792 + idx];
    s2L[idx] = s2g[n * 1792 + idx];
  }
  __syncthreads();
  const int lane = tid & 63, wave = tid >> 6;
  for (int p = wave; p < 49; p += 4) {
    int i = p / 7, j = p - i * 7;
    float ex[4];
    float mx = -1e30f;
    #pragma unroll
    for (int q = 0; q < 4; ++q) {
      int c = lane + q * 64;
      float e = s1L[i * 256 + c] + s2L[j * 256 + c];
      e = (e > 0.f) ? e : LRELU_ALPHA * e;
      ex[q] = e;
      mx = fmaxf(mx, e);
    }
    #pragma unroll
    for (int off = 32; off; off >>= 1) mx = fmaxf(mx, __shfl_xor(mx, off));
    float sm = 0.f;
    #pragma unroll
    for (int q = 0; q < 4; ++q) {
      ex[q] = __expf(ex[q] - mx);
      sm += ex[q];
    }
    #pragma unroll
    for (int off = 32; off; off >>= 1) sm += __shfl_xor(sm, off);
    float inv = 1.0f / sm;
    #pragma unroll
    for (int q = 0; q < 4; ++q) {
      int c = lane + q * 64;
      att[((size_t)n * 256 + c) * 49 + p] = ex[q] * inv;
    }
  }
}

// ---------------- kA_stage: PROBE — staging phase x4 (in-bounds reduce) -----
__global__ __launch_bounds__(256) void kA_stage(const float* __restrict__ h,
                                                float* __restrict__ probe) {
  __shared__ short As[56 * 264];  // 14784 shorts
  const int blk = blockIdx.x;
  const int n = blk >> 5, cb = blk & 31;
  const int tid = threadIdx.x;
  for (int pass = 0; pass < 4; ++pass) {
    const int c8 = tid >> 5;
    const int t0 = (tid & 31) * 8;
    const float* src = h + (size_t)((n * 256 + cb * 8 + c8)) * 1792 + t0 * 7;
    #pragma unroll
    for (int th = 0; th < 2; ++th) {
      float4 x[7];
      #pragma unroll
      for (int i = 0; i < 7; ++i)
        x[i] = reinterpret_cast<const float4*>(src + th * 28)[i];
      const float* xf = reinterpret_cast<const float*>(x);
      #pragma unroll
      for (int v = 0; v < 7; ++v) {
        short4v row;
        #pragma unroll
        for (int dt = 0; dt < 4; ++dt) row[dt] = f2bf(xf[dt * 7 + v]);
        *reinterpret_cast<short4v*>(As + (c8 * 7 + v) * 264 + t0 + th * 4) = row;
      }
    }
    asm volatile("" ::: "memory");  // defeat cross-pass CSE/hoist
    __syncthreads();
  }
  // strictly in-bounds reduction (max idx 255+8000=8255 < 14784)
  float s = (float)As[tid] + (float)As[tid + 4000] + (float)As[tid + 8000];
  probe[(size_t)blk * 256 + tid] = s;
}

// ---------------- kB_mfma: PROBE — MFMA k-loop x4 ----------------
__global__ __launch_bounds__(256) void kB_mfma(const float* __restrict__ h,
                                               const __hip_bfloat16* __restrict__ Wt,
                                               float* __restrict__ probe) {
  __shared__ short As[56 * 264];
  const int blk = blockIdx.x;
  const int n = blk >> 5, cb = blk & 31;
  const int tid = threadIdx.x;
  {
    const int c8 = tid >> 5;
    const int t0 = (tid & 31) * 8;
    const float* src = h + (size_t)((n * 256 + cb * 8 + c8)) * 1792 + t0 * 7;
    #pragma unroll
    for (int th = 0; th < 2; ++th) {
      float4 x[7];
      #pragma unroll
      for (int i = 0; i < 7; ++i)
        x[i] = reinterpret_cast<const float4*>(src + th * 28)[i];
      const float* xf = reinterpret_cast<const float*>(x);
      #pragma unroll
      for (int v = 0; v < 7; ++v) {
        short4v row;
        #pragma unroll
        for (int dt = 0; dt < 4; ++dt) row[dt] = f2bf(xf[dt * 7 + v]);
        *reinterpret_cast<short4v*>(As + (c8 * 7 + v) * 264 + t0 + th * 4) = row;
      }
    }
  }
  __syncthreads();

  const int lane = tid & 63, wave = tid >> 6;
  const int lr = lane & 15, lk = lane >> 4;
  const int f_base = wave * 64;
  f32x4 acc[4][4];
  #pragma unroll
  for (int mt = 0; mt < 4; ++mt)
    #pragma unroll
    for (int ft = 0; ft < 4; ++ft) acc[mt][ft] = (f32x4){0.f, 0.f, 0.f, 0.f};
  const short* WtS = reinterpret_cast<const short*>(Wt);
  int rowm[4];
  #pragma unroll
  for (int mt = 0; mt < 4; ++mt) {
    int m = mt * 16 + lr;
    rowm[mt] = (m < 56) ? m : 55;
  }

  for (int pass = 0; pass < 4; ++pass) {
    #pragma unroll
    for (int kb = 0; kb < 8; ++kb) {
      short8 bfrag[4];
      #pragma unroll
      for (int ft = 0; ft < 4; ++ft)
        bfrag[ft] = *reinterpret_cast<const short8*>(
            WtS + (f_base + ft * 16 + lr) * 256 + kb * 32 + lk * 8);
      #pragma unroll
      for (int mt = 0; mt < 4; ++mt) {
        short8 afrag = *reinterpret_cast<const short8*>(
            As + rowm[mt] * 264 + kb * 32 + lk * 8);
        #pragma unroll
        for (int ft = 0; ft < 4; ++ft)
          acc[mt][ft] = __builtin_amdgcn_mfma_f32_16x16x32_bf16(
              afrag, bfrag[ft], acc[mt][ft], 0, 0, 0);
      }
    }
    asm volatile("" ::: "memory");  // defeat cross-pass CSE/hoist
  }
  float s = 0.f;
  #pragma unroll
  for (int mt = 0; mt < 4; ++mt)
    #pragma unroll
    for (int ft = 0; ft < 4; ++ft)
      s += acc[mt][ft][0] + acc[mt][ft][1] + acc[mt][ft][2] + acc[mt][ft][3];
  probe[(size_t)blk * 256 + tid] = s;
}

// ---------------- KC: fused GEMM + aggregation + ELU (round-6 exact) --------
__global__ __launch_bounds__(256) void kC(const float* __restrict__ h,
                                          const __hip_bfloat16* __restrict__ Wt,
                                          const float* __restrict__ att,
                                          const float* __restrict__ adjn,
                                          float* __restrict__ out) {
  __shared__ short As[56 * 264];   // h-tile, then D repack
  __shared__ float attL[392];      // 8 c x 49
  __shared__ float adjL[49];
  __shared__ float Ml[392];        // 8 c x (j*7+v)
  const int blk = blockIdx.x;
  const int n = blk >> 5, cb = blk & 31;
  const int tid = threadIdx.x;

  {
    const int c8 = tid >> 5;
    const int t0 = (tid & 31) * 8;
    const float* src = h + (size_t)((n * 256 + cb * 8 + c8)) * 1792 + t0 * 7;
    #pragma unroll
    for (int th = 0; th < 2; ++th) {
      float4 x[7];
      #pragma unroll
      for (int i = 0; i < 7; ++i)
        x[i] = reinterpret_cast<const float4*>(src + th * 28)[i];
      const float* xf = reinterpret_cast<const float*>(x);
      #pragma unroll
      for (int v = 0; v < 7; ++v) {
        short4v row;
        #pragma unroll
        for (int dt = 0; dt < 4; ++dt) row[dt] = f2bf(xf[dt * 7 + v]);
        *reinterpret_cast<short4v*>(As + (c8 * 7 + v) * 264 + t0 + th * 4) = row;
      }
    }
  }
  for (int idx = tid; idx < 392; idx += 256)
    attL[idx] = att[(size_t)(n * 256 + cb * 8) * 49 + idx];
  if (tid < 49) adjL[tid] = adjn[tid];
  __syncthreads();

  const int lane = tid & 63, wave = tid >> 6;
  const int lr = lane & 15, lk = lane >> 4;
  const int f_base = wave * 64;

  f32x4 acc[4][4];
  #pragma unroll
  for (int mt = 0; mt < 4; ++mt)
    #pragma unroll
    for (int ft = 0; ft < 4; ++ft) acc[mt][ft] = (f32x4){0.f, 0.f, 0.f, 0.f};

  const short* WtS = reinterpret_cast<const short*>(Wt);
  int rowm[4];
  #pragma unroll
  for (int mt = 0; mt < 4; ++mt) {
    int m = mt * 16 + lr;
    rowm[mt] = (m < 56) ? m : 55;
  }

  #pragma unroll
  for (int kb = 0; kb < 8; ++kb) {
    short8 bfrag[4];
    #pragma unroll
    for (int ft = 0; ft < 4; ++ft)
      bfrag[ft] = *reinterpret_cast<const short8*>(
          WtS + (f_base + ft * 16 + lr) * 256 + kb * 32 + lk * 8);
    #pragma unroll
    for (int mt = 0; mt < 4; ++mt) {
      short8 afrag = *reinterpret_cast<const short8*>(
          As + rowm[mt] * 264 + kb * 32 + lk * 8);
      #pragma unroll
      for (int ft = 0; ft < 4; ++ft)
        acc[mt][ft] = __builtin_amdgcn_mfma_f32_16x16x32_bf16(afrag, bfrag[ft],
                                                              acc[mt][ft], 0, 0, 0);
    }
  }

  for (int idx = tid; idx < 392; idx += 256) {
    int c = idx / 49;
    int r = idx - c * 49;
    int j = r / 7;
    int v = r - j * 7;
    float s = 0.f;
    #pragma unroll
    for (int i = 0; i < 7; ++i) s += attL[c * 49 + i * 7 + j] * adjL[i * 7 + v];
    Ml[idx] = s;
  }

  __syncthreads();

  #pragma unroll
  for (int mt = 0; mt < 4; ++mt) {
    #pragma unroll
    for (int j = 0; j < 4; ++j) {
      int m = mt * 16 + lk * 4 + j;
      if (m < 56) {
        #pragma unroll
        for (int ft = 0; ft < 4; ++ft)
          As[m * 264 + f_base + ft * 16 + lr] = f2bf(acc[mt][ft][j]);
      }
    }
  }
  __syncthreads();

  // round-6 exact epilogue: direct per-thread stores (28 B contiguous each)
  const unsigned short* AsU = reinterpret_cast<const unsigned short*>(As);
  float* dst = out + (size_t)(n * 256 + cb * 8) * 1792 + tid * 7;
  #pragma unroll
  for (int c8 = 0; c8 < 8; ++c8) {
    float wh[7];
    #pragma unroll
    for (int j = 0; j < 7; ++j) wh[j] = bf2f(AsU[(c8 * 7 + j) * 264 + tid]);
    const float* Mc = Ml + c8 * 49;
    float* dc = dst + c8 * 1792;
    #pragma unroll
    for (int v = 0; v < 7; ++v) {
      float o = 0.f;
      #pragma unroll
      for (int j = 0; j < 7; ++j) o += wh[j] * Mc[j * 7 + v];
      o = (o > 0.f) ? o : (__expf(o) - 1.f);
      dc[v] = o;
    }
  }
}

extern "C" void kernel_launch(void* const* d_in, const int* in_sizes, int n_in,
                              void* d_out, int out_size, void* d_ws, size_t ws_size,
                              hipStream_t stream) {
  const float* h = (const float*)d_in[0];
  const float* W = (const float*)d_in[1];
  const float* a = (const float*)d_in[2];
  const float* B = (const float*)d_in[3];
  float* out = (float*)d_out;
  char* ws = (char*)d_ws;

  __hip_bfloat16* Wt = (__hip_bfloat16*)(ws + 0);  // 131072
  float* adjn = (float*)(ws + 131072);             // 256
  float* Wa   = (float*)(ws + 131328);             // 2048
  float* s1g  = (float*)(ws + 133376);             // 458752
  float* s2g  = (float*)(ws + 592128);             // 458752
  float* att  = (float*)(ws + 1050880);            // 3211264 (end 4262144)
  float* probeA = (float*)(ws + (size_t)8 * 1024 * 1024);   // 2 MB
  float* probeB = (float*)(ws + (size_t)16 * 1024 * 1024);  // 2 MB

  k0_wt<<<256, 256, 0, stream>>>(W, Wt);
  k0_wa<<<256, 64, 0, stream>>>(W, a, Wa);
  k0_adj<<<1, 64, 0, stream>>>(B, adjn);
  k1s<<<1024, 256, 0, stream>>>(h, Wa, s1g, s2g);
  k2_soft<<<64, 256, 0, stream>>>(s1g, s2g, att);
  kA_stage<<<2048, 256, 0, stream>>>(h, probeA);
  kB_mfma<<<2048, 256, 0, stream>>>(h, Wt, probeB);
  kC<<<2048, 256, 0, stream>>>(h, Wt, att, adjn, out);
}